// Round 1
// baseline (756.514 us; speedup 1.0000x reference)
//
#include <hip/hip_runtime.h>
#include <math.h>

typedef __bf16 bf16_t;
typedef __bf16 bf16x8_t __attribute__((ext_vector_type(8)));
typedef __bf16 bf16x4_t __attribute__((ext_vector_type(4)));
typedef float f32x4_t __attribute__((ext_vector_type(4)));

#define MFMA(a, b, c) __builtin_amdgcn_mfma_f32_16x16x32_bf16((a), (b), (c), 0, 0, 0)

// ---- workspace layout (bytes) ----
#define WS_WQKV 0u           // 576*192 bf16 = 221184
#define WS_WPROJ 221184u     // 192*192 bf16 = 73728
#define WS_QBIAS 294912u     // 576 f32 = 2304
#define WS_SCALE 297216u     // 6 f32
#define WS_TBL 297472u       // 225*6 f32 = 5400
#define WS_BIAS16 303104u    // 6*64*64 f32 = 98304 -> end 401408

// ============ K1: CPB table: tbl[t][h] = sum_k relu(c@w1^T+b1)[k] * w2[h][k] ============
__global__ __launch_bounds__(64) void cpb_table_kernel(
    const float* __restrict__ w1, const float* __restrict__ b1,
    const float* __restrict__ w2, float* __restrict__ tbl) {
  int t = blockIdx.x;  // 0..224
  int lane = threadIdx.x;
  int dh = t / 15 - 7, dw = t % 15 - 7;
  float th = (float)dh * (8.0f / 7.0f);
  float tw = (float)dw * (8.0f / 7.0f);
  float c0 = copysignf(log2f(fabsf(th) + 1.0f) / 3.0f, th);
  float c1 = copysignf(log2f(fabsf(tw) + 1.0f) / 3.0f, tw);
  float acc[6] = {0.f, 0.f, 0.f, 0.f, 0.f, 0.f};
  for (int k = lane; k < 512; k += 64) {
    float hv = fmaxf(w1[2 * k] * c0 + w1[2 * k + 1] * c1 + b1[k], 0.0f);
#pragma unroll
    for (int hh = 0; hh < 6; ++hh) acc[hh] += hv * w2[hh * 512 + k];
  }
#pragma unroll
  for (int hh = 0; hh < 6; ++hh) {
#pragma unroll
    for (int m = 1; m < 64; m <<= 1) acc[hh] += __shfl_xor(acc[hh], m, 64);
  }
  if (lane == 0) {
#pragma unroll
    for (int hh = 0; hh < 6; ++hh) tbl[t * 6 + hh] = acc[hh];
  }
}

// ============ K2: weight bf16 convert + qkv bias + scales + bias16 gather ============
__global__ __launch_bounds__(256) void prep_kernel(
    const float* __restrict__ qkv_w, const float* __restrict__ proj_w,
    const float* __restrict__ q_bias, const float* __restrict__ v_bias,
    const float* __restrict__ logit_scale, const float* __restrict__ tbl,
    bf16_t* __restrict__ wqkv, bf16_t* __restrict__ wproj,
    float* __restrict__ qbias, float* __restrict__ scalev,
    float* __restrict__ bias16) {
  int id = blockIdx.x * 256 + threadIdx.x;
  if (id < 110592) {
    wqkv[id] = (bf16_t)qkv_w[id];
  } else if (id < 147456) {
    int i = id - 110592;
    wproj[i] = (bf16_t)proj_w[i];
  } else if (id < 148032) {
    int i = id - 147456;
    float bv = (i < 192) ? q_bias[i] : ((i < 384) ? 0.0f : v_bias[i - 384]);
    qbias[i] = bv;
  } else if (id < 148038) {
    int hh = id - 148032;
    scalev[hh] = expf(fminf(logit_scale[hh], logf(100.0f)));
  } else if (id < 172614) {
    int i = id - 148038;  // h*4096 + q*64 + k
    int hh = i >> 12;
    int nm = i & 4095;
    int n = nm >> 6, m = nm & 63;  // n = query token, m = key token
    int i1 = n >> 3, j1 = n & 7, i2 = m >> 3, j2 = m & 7;
    int rpi = (i1 - i2 + 7) * 15 + (j1 - j2 + 7);
    float v = tbl[rpi * 6 + hh];
    bias16[i] = 16.0f / (1.0f + __expf(-v));
  }
}

// ============ main fused kernel: one block = one window, 12 waves = 6 heads x 2 halves ============
// LDS map (78848 B total -> 2 blocks/CU in the 160 KiB pool):
//  [0,25600)      xs  : x bf16 [64 tok][stride 200]
//                       -> after B1.5: Q-scratch [64 tok][stride 200] cols h*32+ch (wave-local)
//                       -> after B2: low part of P
//  [25600,51200)  ks  : K bf16 [64 tok][stride 200] cols h*32+ch
//                       -> after B2: high part of P
//  P (alias [0,50176)): [64 m][stride 392], cols h*64+n (wave-local rows/cols)
//  [51200,78848)  vts : V^T bf16 [192 ch][stride 72]
//                       -> after B2.5: os [64 tok][stride 200] in [51200,76800)
//  mask + bias16 are read straight from global (both L2-resident tables).
__global__ __launch_bounds__(768, 6) void wattn_kernel(
    const float* __restrict__ x, const float* __restrict__ mask,
    const bf16_t* __restrict__ wqkv, const bf16_t* __restrict__ wproj,
    const float* __restrict__ qbias, const float* __restrict__ scalev,
    const float* __restrict__ bias16, const float* __restrict__ proj_b,
    float* __restrict__ out, int nw) {
  __shared__ __align__(16) char smem[78848];
  bf16_t* xs = (bf16_t*)smem;               // [64][200]; later Q-scratch; later P low
  bf16_t* ksv = (bf16_t*)(smem + 25600);    // [64][200]; later P high
  bf16_t* vts = (bf16_t*)(smem + 51200);    // [192][72]; later os
  bf16_t* Ps = (bf16_t*)smem;               // [64][392]
  bf16_t* os = (bf16_t*)(smem + 51200);     // [64][200]

  const int tid = threadIdx.x;
  const int wave = tid >> 6, lane = tid & 63;
  const int h = wave >> 1, s = wave & 1;
  const int quad = lane >> 4, col = lane & 15;
  const int b = blockIdx.x;

  // ---- phase 0: stage x (fp32->bf16), 16 elems/thread, b128 LDS writes ----
  {
    const float4* xg = (const float4*)(x + (size_t)b * 12288);
    float4 v0 = xg[4 * tid + 0];
    float4 v1 = xg[4 * tid + 1];
    float4 v2 = xg[4 * tid + 2];
    float4 v3 = xg[4 * tid + 3];
    int row = tid / 12;          // 0..63
    int cc = (tid % 12) * 16;    // 0..176
    bf16x8_t p0 = {(bf16_t)v0.x, (bf16_t)v0.y, (bf16_t)v0.z, (bf16_t)v0.w,
                   (bf16_t)v1.x, (bf16_t)v1.y, (bf16_t)v1.z, (bf16_t)v1.w};
    bf16x8_t p1 = {(bf16_t)v2.x, (bf16_t)v2.y, (bf16_t)v2.z, (bf16_t)v2.w,
                   (bf16_t)v3.x, (bf16_t)v3.y, (bf16_t)v3.z, (bf16_t)v3.w};
    *(bf16x8_t*)(xs + row * 200 + cc) = p0;
    *(bf16x8_t*)(xs + row * 200 + cc + 8) = p1;
  }
  __syncthreads();  // B1

  const float sc_h = scalev[h];
  const int mrow0 = 32 * s + col;
  const int mrow1 = mrow0 + 16;
  const int koff = quad * 8;
  const f32x4_t zz = {0.f, 0.f, 0.f, 0.f};

  // Q carried across B1.5 in registers (8 VGPRs), written to scratch after barrier
  bf16_t qreg[2][2][4];

  // ---- phase 1: QKV GEMM, order K,V,Q so Q's register span is minimal ----
#pragma unroll
  for (int gi = 0; gi < 3; ++gi) {
    const int g = (gi == 0) ? 1 : ((gi == 1) ? 2 : 0);  // K, V, Q
    const int nbase = g * 192 + h * 32;
    f32x4_t a00 = zz, a01 = zz, a10 = zz, a11 = zz;
#pragma unroll
    for (int kk = 0; kk < 6; ++kk) {
      int k0 = kk * 32 + koff;
      bf16x8_t fa0 = *(const bf16x8_t*)(xs + mrow0 * 200 + k0);
      bf16x8_t fa1 = *(const bf16x8_t*)(xs + mrow1 * 200 + k0);
      bf16x8_t fb0 = *(const bf16x8_t*)(wqkv + (size_t)(nbase + col) * 192 + k0);
      bf16x8_t fb1 = *(const bf16x8_t*)(wqkv + (size_t)(nbase + 16 + col) * 192 + k0);
      a00 = MFMA(fa0, fb0, a00);
      a01 = MFMA(fa0, fb1, a01);
      a10 = MFMA(fa1, fb0, a10);
      a11 = MFMA(fa1, fb1, a11);
    }
    float bn0 = qbias[nbase + col];
    float bn1 = qbias[nbase + 16 + col];
    if (g == 2) {
      // V: add bias, store transposed [chan][token]
#pragma unroll
      for (int mi2 = 0; mi2 < 2; ++mi2) {
        f32x4_t va = mi2 ? a10 : a00;
        f32x4_t vb = mi2 ? a11 : a01;
#pragma unroll
        for (int r = 0; r < 4; ++r) {
          int token = (2 * s + mi2) * 16 + quad * 4 + r;
          vts[(h * 32 + col) * 72 + token] = (bf16_t)(va[r] + bn0);
          vts[(h * 32 + 16 + col) * 72 + token] = (bf16_t)(vb[r] + bn1);
        }
      }
    } else {
      // q or k: add bias, L2-normalize rows (d=32 across 16 lanes x 2 tiles)
      float mult = (g == 0) ? sc_h : 1.0f;
#pragma unroll
      for (int mi2 = 0; mi2 < 2; ++mi2) {
        f32x4_t va = mi2 ? a10 : a00;
        f32x4_t vb = mi2 ? a11 : a01;
#pragma unroll
        for (int r = 0; r < 4; ++r) {
          float v0 = va[r] + bn0, v1 = vb[r] + bn1;
          float ss = v0 * v0 + v1 * v1;
          ss += __shfl_xor(ss, 1, 64);
          ss += __shfl_xor(ss, 2, 64);
          ss += __shfl_xor(ss, 4, 64);
          ss += __shfl_xor(ss, 8, 64);
          float inv = mult / fmaxf(sqrtf(ss), 1e-12f);
          if (g == 1) {
            int token = (2 * s + mi2) * 16 + quad * 4 + r;
            ksv[token * 200 + h * 32 + col] = (bf16_t)(v0 * inv);
            ksv[token * 200 + h * 32 + 16 + col] = (bf16_t)(v1 * inv);
          } else {
            qreg[mi2][0][r] = (bf16_t)(v0 * inv);
            qreg[mi2][1][r] = (bf16_t)(v1 * inv);
          }
        }
      }
    }
  }
  __syncthreads();  // B1.5: ks/vts visible; all xs reads done -> xs reusable as Q scratch

  // ---- Q transpose scratch in dead xs region (wave-local rows & cols, no barrier) ----
  bf16_t* Qs = xs;
#pragma unroll
  for (int mi2 = 0; mi2 < 2; ++mi2) {
#pragma unroll
    for (int r = 0; r < 4; ++r) {
      int token = (2 * s + mi2) * 16 + quad * 4 + r;
      Qs[token * 200 + h * 32 + col] = qreg[mi2][0][r];
      Qs[token * 200 + h * 32 + 16 + col] = qreg[mi2][1][r];
    }
  }

  // ---- phase 2: attn = (scaled qn) @ kn^T, K=32 single MFMA step ----
  f32x4_t at[2][4];
  {
    bf16x8_t aq0 = *(const bf16x8_t*)(Qs + mrow0 * 200 + h * 32 + koff);
    bf16x8_t aq1 = *(const bf16x8_t*)(Qs + mrow1 * 200 + h * 32 + koff);
#pragma unroll
    for (int ni = 0; ni < 4; ++ni) {
      bf16x8_t bk = *(const bf16x8_t*)(ksv + (ni * 16 + col) * 200 + h * 32 + koff);
      at[0][ni] = MFMA(aq0, bk, zz);
      at[1][ni] = MFMA(aq1, bk, zz);
    }
  }

  // ---- softmax rows (in-register; cpb bias + mask straight from L2) ----
  float p[2][4][4];
  const float* bg = bias16 + h * 4096;
  const float* mg = mask + (size_t)(b % nw) * 4096;
#pragma unroll
  for (int mi2 = 0; mi2 < 2; ++mi2) {
#pragma unroll
    for (int r = 0; r < 4; ++r) {
      int m = (2 * s + mi2) * 16 + quad * 4 + r;
      float vals[4];
#pragma unroll
      for (int ni = 0; ni < 4; ++ni) {
        int n = ni * 16 + col;
        vals[ni] = at[mi2][ni][r] + bg[m * 64 + n] + mg[m * 64 + n];
      }
      float mx = fmaxf(fmaxf(vals[0], vals[1]), fmaxf(vals[2], vals[3]));
      mx = fmaxf(mx, __shfl_xor(mx, 1, 64));
      mx = fmaxf(mx, __shfl_xor(mx, 2, 64));
      mx = fmaxf(mx, __shfl_xor(mx, 4, 64));
      mx = fmaxf(mx, __shfl_xor(mx, 8, 64));
      float sm = 0.f;
#pragma unroll
      for (int ni = 0; ni < 4; ++ni) {
        vals[ni] = __expf(vals[ni] - mx);
        sm += vals[ni];
      }
      sm += __shfl_xor(sm, 1, 64);
      sm += __shfl_xor(sm, 2, 64);
      sm += __shfl_xor(sm, 4, 64);
      sm += __shfl_xor(sm, 8, 64);
      float inv = 1.0f / sm;
#pragma unroll
      for (int ni = 0; ni < 4; ++ni) p[mi2][ni][r] = vals[ni] * inv;
    }
  }
  __syncthreads();  // B2: all phase-2 LDS reads done -> P may overwrite xs/ks regions

  // ---- write P (bf16 [64][392], cols h*64+n; wave-local rows/cols) ----
#pragma unroll
  for (int mi2 = 0; mi2 < 2; ++mi2) {
#pragma unroll
    for (int ni = 0; ni < 4; ++ni) {
#pragma unroll
      for (int r = 0; r < 4; ++r) {
        int m = (2 * s + mi2) * 16 + quad * 4 + r;
        Ps[m * 392 + h * 64 + ni * 16 + col] = (bf16_t)p[mi2][ni][r];
      }
    }
  }

  // ---- phase 3: O_h = P @ V (K=64 -> 2 steps) ----
  f32x4_t oac[2][2] = {{zz, zz}, {zz, zz}};
#pragma unroll
  for (int kk = 0; kk < 2; ++kk) {
    int k0 = kk * 32 + koff;
    bf16x8_t pa0 = *(const bf16x8_t*)(Ps + mrow0 * 392 + h * 64 + k0);
    bf16x8_t pa1 = *(const bf16x8_t*)(Ps + mrow1 * 392 + h * 64 + k0);
    bf16x8_t vb0 = *(const bf16x8_t*)(vts + (h * 32 + col) * 72 + k0);
    bf16x8_t vb1 = *(const bf16x8_t*)(vts + (h * 32 + 16 + col) * 72 + k0);
    oac[0][0] = MFMA(pa0, vb0, oac[0][0]);
    oac[0][1] = MFMA(pa0, vb1, oac[0][1]);
    oac[1][0] = MFMA(pa1, vb0, oac[1][0]);
    oac[1][1] = MFMA(pa1, vb1, oac[1][1]);
  }
  __syncthreads();  // B2.5: all vts reads done -> os may overwrite vts region

  // ---- stage o (all heads' 32-ch slices -> 64x192, stride 200) ----
#pragma unroll
  for (int mi2 = 0; mi2 < 2; ++mi2) {
#pragma unroll
    for (int ni = 0; ni < 2; ++ni) {
#pragma unroll
      for (int r = 0; r < 4; ++r) {
        int token = (2 * s + mi2) * 16 + quad * 4 + r;
        os[token * 200 + h * 32 + ni * 16 + col] = (bf16_t)oac[mi2][ni][r];
      }
    }
  }
  __syncthreads();  // B3: full o visible

  // ---- phase 4: out = o @ proj_w^T + proj_b ----
  f32x4_t pr[2][2] = {{zz, zz}, {zz, zz}};
#pragma unroll
  for (int kk = 0; kk < 6; ++kk) {
    int k0 = kk * 32 + koff;
    bf16x8_t fa0 = *(const bf16x8_t*)(os + mrow0 * 200 + k0);
    bf16x8_t fa1 = *(const bf16x8_t*)(os + mrow1 * 200 + k0);
    bf16x8_t fb0 = *(const bf16x8_t*)(wproj + (size_t)(h * 32 + col) * 192 + k0);
    bf16x8_t fb1 = *(const bf16x8_t*)(wproj + (size_t)(h * 32 + 16 + col) * 192 + k0);
    pr[0][0] = MFMA(fa0, fb0, pr[0][0]);
    pr[0][1] = MFMA(fa0, fb1, pr[0][1]);
    pr[1][0] = MFMA(fa1, fb0, pr[1][0]);
    pr[1][1] = MFMA(fa1, fb1, pr[1][1]);
  }
  float pb0 = proj_b[h * 32 + col];
  float pb1 = proj_b[h * 32 + 16 + col];
  float* og = out + (size_t)b * 12288;
#pragma unroll
  for (int mi2 = 0; mi2 < 2; ++mi2) {
#pragma unroll
    for (int r = 0; r < 4; ++r) {
      int token = (2 * s + mi2) * 16 + quad * 4 + r;
      og[token * 192 + h * 32 + col] = pr[mi2][0][r] + pb0;
      og[token * 192 + h * 32 + 16 + col] = pr[mi2][1][r] + pb1;
    }
  }
}

extern "C" void kernel_launch(void* const* d_in, const int* in_sizes, int n_in,
                              void* d_out, int out_size, void* d_ws, size_t ws_size,
                              hipStream_t stream) {
  const float* x = (const float*)d_in[0];
  const float* mask = (const float*)d_in[1];
  const float* qkv_w = (const float*)d_in[2];
  const float* q_bias = (const float*)d_in[3];
  const float* v_bias = (const float*)d_in[4];
  const float* logit_scale = (const float*)d_in[5];
  const float* cpb_w1 = (const float*)d_in[6];
  const float* cpb_b1 = (const float*)d_in[7];
  const float* cpb_w2 = (const float*)d_in[8];
  const float* proj_w = (const float*)d_in[9];
  const float* proj_b = (const float*)d_in[10];
  float* out = (float*)d_out;

  char* ws = (char*)d_ws;
  bf16_t* wqkv = (bf16_t*)(ws + WS_WQKV);
  bf16_t* wproj = (bf16_t*)(ws + WS_WPROJ);
  float* qbias = (float*)(ws + WS_QBIAS);
  float* scalev = (float*)(ws + WS_SCALE);
  float* tbl = (float*)(ws + WS_TBL);
  float* bias16 = (float*)(ws + WS_BIAS16);

  const int nwin = in_sizes[0] / 12288;   // 4096
  const int nw = in_sizes[1] / 4096;      // 64 mask windows

  cpb_table_kernel<<<dim3(225), dim3(64), 0, stream>>>(cpb_w1, cpb_b1, cpb_w2, tbl);
  prep_kernel<<<dim3(675), dim3(256), 0, stream>>>(qkv_w, proj_w, q_bias, v_bias,
                                                   logit_scale, tbl, wqkv, wproj,
                                                   qbias, scalev, bias16);
  wattn_kernel<<<dim3(nwin), dim3(768), 0, stream>>>(x, mask, wqkv, wproj, qbias,
                                                     scalev, bias16, proj_b, out, nw);
}

// Round 2
// 714.342 us; speedup vs baseline: 1.0590x; 1.0590x over previous
//
#include <hip/hip_runtime.h>
#include <math.h>

typedef __bf16 bf16_t;
typedef __bf16 bf16x8_t __attribute__((ext_vector_type(8)));
typedef __bf16 bf16x4_t __attribute__((ext_vector_type(4)));
typedef float f32x4_t __attribute__((ext_vector_type(4)));

#define MFMA(a, b, c) __builtin_amdgcn_mfma_f32_16x16x32_bf16((a), (b), (c), 0, 0, 0)

// ---- workspace layout (bytes) ----
#define WS_WQKV 0u           // 576*192 bf16 = 221184
#define WS_WPROJ 221184u     // 192*192 bf16 = 73728
#define WS_QBIAS 294912u     // 576 f32 = 2304
#define WS_SCALE 297216u     // 6 f32
#define WS_TBL 297472u       // 225*6 f32 = 5400
#define WS_BIAS16 303104u    // 6*64*64 f32 = 98304 -> end 401408

// ============ K1: CPB table: tbl[t][h] = sum_k relu(c@w1^T+b1)[k] * w2[h][k] ============
__global__ __launch_bounds__(64) void cpb_table_kernel(
    const float* __restrict__ w1, const float* __restrict__ b1,
    const float* __restrict__ w2, float* __restrict__ tbl) {
  int t = blockIdx.x;  // 0..224
  int lane = threadIdx.x;
  int dh = t / 15 - 7, dw = t % 15 - 7;
  float th = (float)dh * (8.0f / 7.0f);
  float tw = (float)dw * (8.0f / 7.0f);
  float c0 = copysignf(log2f(fabsf(th) + 1.0f) / 3.0f, th);
  float c1 = copysignf(log2f(fabsf(tw) + 1.0f) / 3.0f, tw);
  float acc[6] = {0.f, 0.f, 0.f, 0.f, 0.f, 0.f};
  for (int k = lane; k < 512; k += 64) {
    float hv = fmaxf(w1[2 * k] * c0 + w1[2 * k + 1] * c1 + b1[k], 0.0f);
#pragma unroll
    for (int hh = 0; hh < 6; ++hh) acc[hh] += hv * w2[hh * 512 + k];
  }
#pragma unroll
  for (int hh = 0; hh < 6; ++hh) {
#pragma unroll
    for (int m = 1; m < 64; m <<= 1) acc[hh] += __shfl_xor(acc[hh], m, 64);
  }
  if (lane == 0) {
#pragma unroll
    for (int hh = 0; hh < 6; ++hh) tbl[t * 6 + hh] = acc[hh];
  }
}

// ============ K2: weight bf16 convert + qkv bias + scales + bias16 gather ============
__global__ __launch_bounds__(256) void prep_kernel(
    const float* __restrict__ qkv_w, const float* __restrict__ proj_w,
    const float* __restrict__ q_bias, const float* __restrict__ v_bias,
    const float* __restrict__ logit_scale, const float* __restrict__ tbl,
    bf16_t* __restrict__ wqkv, bf16_t* __restrict__ wproj,
    float* __restrict__ qbias, float* __restrict__ scalev,
    float* __restrict__ bias16) {
  int id = blockIdx.x * 256 + threadIdx.x;
  if (id < 110592) {
    wqkv[id] = (bf16_t)qkv_w[id];
  } else if (id < 147456) {
    int i = id - 110592;
    wproj[i] = (bf16_t)proj_w[i];
  } else if (id < 148032) {
    int i = id - 147456;
    float bv = (i < 192) ? q_bias[i] : ((i < 384) ? 0.0f : v_bias[i - 384]);
    qbias[i] = bv;
  } else if (id < 148038) {
    int hh = id - 148032;
    scalev[hh] = expf(fminf(logit_scale[hh], logf(100.0f)));
  } else if (id < 172614) {
    int i = id - 148038;  // h*4096 + q*64 + k
    int hh = i >> 12;
    int nm = i & 4095;
    int n = nm >> 6, m = nm & 63;  // n = query token, m = key token
    int i1 = n >> 3, j1 = n & 7, i2 = m >> 3, j2 = m & 7;
    int rpi = (i1 - i2 + 7) * 15 + (j1 - j2 + 7);
    float v = tbl[rpi * 6 + hh];
    bias16[i] = 16.0f / (1.0f + __expf(-v));
  }
}

// ============ main fused kernel: one block = one window, 12 waves = 6 heads x 2 halves ============
// LDS map (78848 B total -> 2 blocks/CU in the 160 KiB pool):
//  [0,25600)      xs  : x bf16 [64 tok][stride 200]
//                       -> after B1.5: Q-scratch [64 tok][stride 200] cols h*32+ch (wave-local)
//                       -> after B2: low part of P
//  [25600,51200)  ks  : K bf16 [64 tok][stride 200] cols h*32+ch
//                       -> after B2: high part of P
//  P (alias [0,50176)): [64 m][stride 392], cols h*64+n (wave-local rows/cols)
//  [51200,78848)  vts : V^T bf16 [192 ch][stride 72]
//                       -> after B2.5: os [64 tok][stride 200] in [51200,76800)
//  mask + bias16 are read straight from global (both L2-resident tables).
// NOTE: plain __launch_bounds__(768) — adding a min-waves hint (768,6) strangled the
// allocator to 40 VGPRs and generated ~850 MB/launch of scratch spill traffic (R1).
__global__ __launch_bounds__(768) void wattn_kernel(
    const float* __restrict__ x, const float* __restrict__ mask,
    const bf16_t* __restrict__ wqkv, const bf16_t* __restrict__ wproj,
    const float* __restrict__ qbias, const float* __restrict__ scalev,
    const float* __restrict__ bias16, const float* __restrict__ proj_b,
    float* __restrict__ out, int nw) {
  __shared__ __align__(16) char smem[78848];
  bf16_t* xs = (bf16_t*)smem;               // [64][200]; later Q-scratch; later P low
  bf16_t* ksv = (bf16_t*)(smem + 25600);    // [64][200]; later P high
  bf16_t* vts = (bf16_t*)(smem + 51200);    // [192][72]; later os
  bf16_t* Ps = (bf16_t*)smem;               // [64][392]
  bf16_t* os = (bf16_t*)(smem + 51200);     // [64][200]

  const int tid = threadIdx.x;
  const int wave = tid >> 6, lane = tid & 63;
  const int h = wave >> 1, s = wave & 1;
  const int quad = lane >> 4, col = lane & 15;
  const int b = blockIdx.x;

  // ---- phase 0: stage x (fp32->bf16), 16 elems/thread, b128 LDS writes ----
  {
    const float4* xg = (const float4*)(x + (size_t)b * 12288);
    float4 v0 = xg[4 * tid + 0];
    float4 v1 = xg[4 * tid + 1];
    float4 v2 = xg[4 * tid + 2];
    float4 v3 = xg[4 * tid + 3];
    int row = tid / 12;          // 0..63
    int cc = (tid % 12) * 16;    // 0..176
    bf16x8_t p0 = {(bf16_t)v0.x, (bf16_t)v0.y, (bf16_t)v0.z, (bf16_t)v0.w,
                   (bf16_t)v1.x, (bf16_t)v1.y, (bf16_t)v1.z, (bf16_t)v1.w};
    bf16x8_t p1 = {(bf16_t)v2.x, (bf16_t)v2.y, (bf16_t)v2.z, (bf16_t)v2.w,
                   (bf16_t)v3.x, (bf16_t)v3.y, (bf16_t)v3.z, (bf16_t)v3.w};
    *(bf16x8_t*)(xs + row * 200 + cc) = p0;
    *(bf16x8_t*)(xs + row * 200 + cc + 8) = p1;
  }
  __syncthreads();  // B1

  const float sc_h = scalev[h];
  const int mrow0 = 32 * s + col;
  const int mrow1 = mrow0 + 16;
  const int koff = quad * 8;
  const f32x4_t zz = {0.f, 0.f, 0.f, 0.f};

  // Q carried across B1.5 in registers (8 VGPRs), written to scratch after barrier
  bf16_t qreg[2][2][4];

  // ---- phase 1: QKV GEMM, order K,V,Q so Q's register span is minimal ----
#pragma unroll
  for (int gi = 0; gi < 3; ++gi) {
    const int g = (gi == 0) ? 1 : ((gi == 1) ? 2 : 0);  // K, V, Q
    const int nbase = g * 192 + h * 32;
    f32x4_t a00 = zz, a01 = zz, a10 = zz, a11 = zz;
#pragma unroll
    for (int kk = 0; kk < 6; ++kk) {
      int k0 = kk * 32 + koff;
      bf16x8_t fa0 = *(const bf16x8_t*)(xs + mrow0 * 200 + k0);
      bf16x8_t fa1 = *(const bf16x8_t*)(xs + mrow1 * 200 + k0);
      bf16x8_t fb0 = *(const bf16x8_t*)(wqkv + (size_t)(nbase + col) * 192 + k0);
      bf16x8_t fb1 = *(const bf16x8_t*)(wqkv + (size_t)(nbase + 16 + col) * 192 + k0);
      a00 = MFMA(fa0, fb0, a00);
      a01 = MFMA(fa0, fb1, a01);
      a10 = MFMA(fa1, fb0, a10);
      a11 = MFMA(fa1, fb1, a11);
    }
    float bn0 = qbias[nbase + col];
    float bn1 = qbias[nbase + 16 + col];
    if (g == 2) {
      // V: add bias, store transposed [chan][token]
#pragma unroll
      for (int mi2 = 0; mi2 < 2; ++mi2) {
        f32x4_t va = mi2 ? a10 : a00;
        f32x4_t vb = mi2 ? a11 : a01;
#pragma unroll
        for (int r = 0; r < 4; ++r) {
          int token = (2 * s + mi2) * 16 + quad * 4 + r;
          vts[(h * 32 + col) * 72 + token] = (bf16_t)(va[r] + bn0);
          vts[(h * 32 + 16 + col) * 72 + token] = (bf16_t)(vb[r] + bn1);
        }
      }
    } else {
      // q or k: add bias, L2-normalize rows (d=32 across 16 lanes x 2 tiles)
      float mult = (g == 0) ? sc_h : 1.0f;
#pragma unroll
      for (int mi2 = 0; mi2 < 2; ++mi2) {
        f32x4_t va = mi2 ? a10 : a00;
        f32x4_t vb = mi2 ? a11 : a01;
#pragma unroll
        for (int r = 0; r < 4; ++r) {
          float v0 = va[r] + bn0, v1 = vb[r] + bn1;
          float ss = v0 * v0 + v1 * v1;
          ss += __shfl_xor(ss, 1, 64);
          ss += __shfl_xor(ss, 2, 64);
          ss += __shfl_xor(ss, 4, 64);
          ss += __shfl_xor(ss, 8, 64);
          float inv = mult / fmaxf(sqrtf(ss), 1e-12f);
          if (g == 1) {
            int token = (2 * s + mi2) * 16 + quad * 4 + r;
            ksv[token * 200 + h * 32 + col] = (bf16_t)(v0 * inv);
            ksv[token * 200 + h * 32 + 16 + col] = (bf16_t)(v1 * inv);
          } else {
            qreg[mi2][0][r] = (bf16_t)(v0 * inv);
            qreg[mi2][1][r] = (bf16_t)(v1 * inv);
          }
        }
      }
    }
  }
  __syncthreads();  // B1.5: ks/vts visible; all xs reads done -> xs reusable as Q scratch

  // ---- Q transpose scratch in dead xs region (wave-local rows & cols, no barrier) ----
  bf16_t* Qs = xs;
#pragma unroll
  for (int mi2 = 0; mi2 < 2; ++mi2) {
#pragma unroll
    for (int r = 0; r < 4; ++r) {
      int token = (2 * s + mi2) * 16 + quad * 4 + r;
      Qs[token * 200 + h * 32 + col] = qreg[mi2][0][r];
      Qs[token * 200 + h * 32 + 16 + col] = qreg[mi2][1][r];
    }
  }

  // ---- phase 2: attn = (scaled qn) @ kn^T, K=32 single MFMA step ----
  f32x4_t at[2][4];
  {
    bf16x8_t aq0 = *(const bf16x8_t*)(Qs + mrow0 * 200 + h * 32 + koff);
    bf16x8_t aq1 = *(const bf16x8_t*)(Qs + mrow1 * 200 + h * 32 + koff);
#pragma unroll
    for (int ni = 0; ni < 4; ++ni) {
      bf16x8_t bk = *(const bf16x8_t*)(ksv + (ni * 16 + col) * 200 + h * 32 + koff);
      at[0][ni] = MFMA(aq0, bk, zz);
      at[1][ni] = MFMA(aq1, bk, zz);
    }
  }

  // ---- softmax rows (in-register; cpb bias + mask straight from L2) ----
  float p[2][4][4];
  const float* bg = bias16 + h * 4096;
  const float* mg = mask + (size_t)(b % nw) * 4096;
#pragma unroll
  for (int mi2 = 0; mi2 < 2; ++mi2) {
#pragma unroll
    for (int r = 0; r < 4; ++r) {
      int m = (2 * s + mi2) * 16 + quad * 4 + r;
      float vals[4];
#pragma unroll
      for (int ni = 0; ni < 4; ++ni) {
        int n = ni * 16 + col;
        vals[ni] = at[mi2][ni][r] + bg[m * 64 + n] + mg[m * 64 + n];
      }
      float mx = fmaxf(fmaxf(vals[0], vals[1]), fmaxf(vals[2], vals[3]));
      mx = fmaxf(mx, __shfl_xor(mx, 1, 64));
      mx = fmaxf(mx, __shfl_xor(mx, 2, 64));
      mx = fmaxf(mx, __shfl_xor(mx, 4, 64));
      mx = fmaxf(mx, __shfl_xor(mx, 8, 64));
      float sm = 0.f;
#pragma unroll
      for (int ni = 0; ni < 4; ++ni) {
        vals[ni] = __expf(vals[ni] - mx);
        sm += vals[ni];
      }
      sm += __shfl_xor(sm, 1, 64);
      sm += __shfl_xor(sm, 2, 64);
      sm += __shfl_xor(sm, 4, 64);
      sm += __shfl_xor(sm, 8, 64);
      float inv = 1.0f / sm;
#pragma unroll
      for (int ni = 0; ni < 4; ++ni) p[mi2][ni][r] = vals[ni] * inv;
    }
  }
  __syncthreads();  // B2: all phase-2 LDS reads done -> P may overwrite xs/ks regions

  // ---- write P (bf16 [64][392], cols h*64+n; wave-local rows/cols) ----
#pragma unroll
  for (int mi2 = 0; mi2 < 2; ++mi2) {
#pragma unroll
    for (int ni = 0; ni < 4; ++ni) {
#pragma unroll
      for (int r = 0; r < 4; ++r) {
        int m = (2 * s + mi2) * 16 + quad * 4 + r;
        Ps[m * 392 + h * 64 + ni * 16 + col] = (bf16_t)p[mi2][ni][r];
      }
    }
  }

  // ---- phase 3: O_h = P @ V (K=64 -> 2 steps) ----
  f32x4_t oac[2][2] = {{zz, zz}, {zz, zz}};
#pragma unroll
  for (int kk = 0; kk < 2; ++kk) {
    int k0 = kk * 32 + koff;
    bf16x8_t pa0 = *(const bf16x8_t*)(Ps + mrow0 * 392 + h * 64 + k0);
    bf16x8_t pa1 = *(const bf16x8_t*)(Ps + mrow1 * 392 + h * 64 + k0);
    bf16x8_t vb0 = *(const bf16x8_t*)(vts + (h * 32 + col) * 72 + k0);
    bf16x8_t vb1 = *(const bf16x8_t*)(vts + (h * 32 + 16 + col) * 72 + k0);
    oac[0][0] = MFMA(pa0, vb0, oac[0][0]);
    oac[0][1] = MFMA(pa0, vb1, oac[0][1]);
    oac[1][0] = MFMA(pa1, vb0, oac[1][0]);
    oac[1][1] = MFMA(pa1, vb1, oac[1][1]);
  }
  __syncthreads();  // B2.5: all vts reads done -> os may overwrite vts region

  // ---- stage o (all heads' 32-ch slices -> 64x192, stride 200) ----
#pragma unroll
  for (int mi2 = 0; mi2 < 2; ++mi2) {
#pragma unroll
    for (int ni = 0; ni < 2; ++ni) {
#pragma unroll
      for (int r = 0; r < 4; ++r) {
        int token = (2 * s + mi2) * 16 + quad * 4 + r;
        os[token * 200 + h * 32 + ni * 16 + col] = (bf16_t)oac[mi2][ni][r];
      }
    }
  }
  __syncthreads();  // B3: full o visible

  // ---- phase 4: out = o @ proj_w^T + proj_b ----
  f32x4_t pr[2][2] = {{zz, zz}, {zz, zz}};
#pragma unroll
  for (int kk = 0; kk < 6; ++kk) {
    int k0 = kk * 32 + koff;
    bf16x8_t fa0 = *(const bf16x8_t*)(os + mrow0 * 200 + k0);
    bf16x8_t fa1 = *(const bf16x8_t*)(os + mrow1 * 200 + k0);
    bf16x8_t fb0 = *(const bf16x8_t*)(wproj + (size_t)(h * 32 + col) * 192 + k0);
    bf16x8_t fb1 = *(const bf16x8_t*)(wproj + (size_t)(h * 32 + 16 + col) * 192 + k0);
    pr[0][0] = MFMA(fa0, fb0, pr[0][0]);
    pr[0][1] = MFMA(fa0, fb1, pr[0][1]);
    pr[1][0] = MFMA(fa1, fb0, pr[1][0]);
    pr[1][1] = MFMA(fa1, fb1, pr[1][1]);
  }
  float pb0 = proj_b[h * 32 + col];
  float pb1 = proj_b[h * 32 + 16 + col];
  float* og = out + (size_t)b * 12288;
#pragma unroll
  for (int mi2 = 0; mi2 < 2; ++mi2) {
#pragma unroll
    for (int r = 0; r < 4; ++r) {
      int token = (2 * s + mi2) * 16 + quad * 4 + r;
      og[token * 192 + h * 32 + col] = pr[mi2][0][r] + pb0;
      og[token * 192 + h * 32 + 16 + col] = pr[mi2][1][r] + pb1;
    }
  }
}

extern "C" void kernel_launch(void* const* d_in, const int* in_sizes, int n_in,
                              void* d_out, int out_size, void* d_ws, size_t ws_size,
                              hipStream_t stream) {
  const float* x = (const float*)d_in[0];
  const float* mask = (const float*)d_in[1];
  const float* qkv_w = (const float*)d_in[2];
  const float* q_bias = (const float*)d_in[3];
  const float* v_bias = (const float*)d_in[4];
  const float* logit_scale = (const float*)d_in[5];
  const float* cpb_w1 = (const float*)d_in[6];
  const float* cpb_b1 = (const float*)d_in[7];
  const float* cpb_w2 = (const float*)d_in[8];
  const float* proj_w = (const float*)d_in[9];
  const float* proj_b = (const float*)d_in[10];
  float* out = (float*)d_out;

  char* ws = (char*)d_ws;
  bf16_t* wqkv = (bf16_t*)(ws + WS_WQKV);
  bf16_t* wproj = (bf16_t*)(ws + WS_WPROJ);
  float* qbias = (float*)(ws + WS_QBIAS);
  float* scalev = (float*)(ws + WS_SCALE);
  float* tbl = (float*)(ws + WS_TBL);
  float* bias16 = (float*)(ws + WS_BIAS16);

  const int nwin = in_sizes[0] / 12288;   // 4096
  const int nw = in_sizes[1] / 4096;      // 64 mask windows

  cpb_table_kernel<<<dim3(225), dim3(64), 0, stream>>>(cpb_w1, cpb_b1, cpb_w2, tbl);
  prep_kernel<<<dim3(675), dim3(256), 0, stream>>>(qkv_w, proj_w, q_bias, v_bias,
                                                   logit_scale, tbl, wqkv, wproj,
                                                   qbias, scalev, bias16);
  wattn_kernel<<<dim3(nwin), dim3(768), 0, stream>>>(x, mask, wqkv, wproj, qbias,
                                                     scalev, bias16, proj_b, out, nw);
}